// Round 8
// baseline (173.318 us; speedup 1.0000x reference)
//
#include <hip/hip_runtime.h>

// Problem dims (hardcoded from reference)
#define T_STEPS 100
#define B_N     128
#define IN_F    512
#define OUT_F   512
#define KPAD    128   // T padded to 128 for MFMA K

// fp64 decay constants: exp(-DT/TAU_*)
#define ALPHA_D 0.8187307530779818   // exp(-1/5)   synaptic
#define BETA_D  0.9512294245007140   // exp(-1/20)  membrane

typedef __attribute__((ext_vector_type(8))) short bf16x8;
typedef __attribute__((ext_vector_type(4))) float f32x4;

static __device__ __forceinline__ unsigned int f2bf(float f) {
    union { float f; unsigned int u; } v; v.f = f;
    return (v.u + 0x7FFFu + ((v.u >> 16) & 1u)) >> 16;   // RNE
}

// ---------------------------------------------------------------------------
// K1: transpose W (OUT x IN) -> Wt (IN x OUT).
// ---------------------------------------------------------------------------
__global__ __launch_bounds__(256) void transposeW(const float* __restrict__ W,
                                                  float* __restrict__ Wt) {
    __shared__ float tile[32][33];
    const int bx = blockIdx.x & 15;   // i-tile
    const int by = blockIdx.x >> 4;   // o-tile
    const int tx = threadIdx.x & 31;
    const int ty = threadIdx.x >> 5;  // 0..7
#pragma unroll
    for (int k = 0; k < 32; k += 8) {
        int o = by * 32 + ty + k;
        tile[ty + k][tx] = W[o * IN_F + bx * 32 + tx];
    }
    __syncthreads();
#pragma unroll
    for (int k = 0; k < 32; k += 8) {
        int i = bx * 32 + ty + k;
        Wt[i * OUT_F + by * 32 + tx] = tile[tx][ty + k];
    }
}

// ---------------------------------------------------------------------------
// K_A: fused grid. Blocks [0, nconv): x -> Xbf bf16 [b][i][kpad] conversion.
// Blocks [nconv, nconv+12800): synaptic current C[t,b,o] in fp64.
// ---------------------------------------------------------------------------
__global__ __launch_bounds__(256) void syn_plus(const float* __restrict__ x,
                                                const float* __restrict__ Wt,
                                                double* __restrict__ C,
                                                unsigned short* __restrict__ Xbf,
                                                int nconv) {
    const int tid = threadIdx.x;

    if ((int)blockIdx.x < nconv) {
        // ---- x_to_bf16: block cb covers (b, i-range of 128) ----
        const int cb = blockIdx.x;
        const int b  = cb & (B_N - 1);
        const int i0 = (cb >> 7) * 128;
#pragma unroll
        for (int r = 0; r < 8; ++r) {
            const int g = tid + r * 256;        // 2048: c(16) x i(128)
            const int i = i0 + (g & 127);
            const int c = g >> 7;               // 16B chunk = 8 t's
            unsigned int h[4];
#pragma unroll
            for (int jj = 0; jj < 4; ++jj) {
                const int t0 = c * 8 + jj * 2, t1 = t0 + 1;
                float v0 = 0.f, v1 = 0.f;
                if (t0 < T_STEPS) v0 = x[(size_t)t0 * (B_N * IN_F) + b * IN_F + i];
                if (t1 < T_STEPS) v1 = x[(size_t)t1 * (B_N * IN_F) + b * IN_F + i];
                h[jj] = f2bf(v0) | (f2bf(v1) << 16);
            }
            *(uint4*)((char*)Xbf + (size_t)(b * IN_F + i) * (KPAD * 2) + c * 16) =
                make_uint4(h[0], h[1], h[2], h[3]);
        }
        return;
    }

    // ---- syn_current ----
    const int tb = (int)blockIdx.x - nconv;     // t*B + b

    __shared__ int s_idx[IN_F];
    __shared__ int s_cnt;

    if (tid < 64) {                      // wave 0 builds ascending active list
        const float* xr = x + (size_t)tb * IN_F;
        int base = 0;
#pragma unroll
        for (int j = 0; j < 8; ++j) {
            const float v = xr[j * 64 + tid];
            const unsigned long long m = __ballot(v > 0.5f);
            if (v > 0.5f) {
                const int pos = base + __popcll(m & ((1ull << tid) - 1ull));
                s_idx[pos] = j * 64 + tid;
            }
            base += __popcll(m);
        }
        if (tid == 0) s_cnt = base;
    }
    __syncthreads();

    const int cnt = s_cnt;
    double c0 = 0.0, c1 = 0.0;
    const float* W0 = Wt + tid;
    const float* W1 = Wt + tid + 256;
    for (int k = 0; k < cnt; ++k) {
        const int i = s_idx[k];          // LDS broadcast (uniform address)
        c0 += (double)W0[(size_t)i * OUT_F];
        c1 += (double)W1[(size_t)i * OUT_F];
    }

    double* Cr = C + (size_t)tb * OUT_F;
    Cr[tid]       = c0;
    Cr[tid + 256] = c1;
}

// ---------------------------------------------------------------------------
// K_B: elementwise LIF scan, one thread per (b,o). fp64 recurrence,
// double-buffered 10-step chunks (static indices only). Emits
// Pbf[b][o][kpad] = bf16(sigma'(U_post) * gamma^(99-t)) when Pq != nullptr.
// ---------------------------------------------------------------------------
#define LIF_STEP(BUF, J, CB)                                                   \
    {                                                                          \
        const int t = (CB) * 10 + (J);                                         \
        I = ALPHA_D * I + BUF[J];                                              \
        U = BETA_D * U + I;                                                    \
        const double Sv = (U >= 1.0) ? 1.0 : 0.0;                              \
        S_out[(size_t)t * N + pos] = (float)Sv;                                \
        Uh[(size_t)(2 * t) * N + pos] = (float)U;                              \
        U -= Sv;                                                               \
        Uh[(size_t)(2 * t + 1) * N + pos] = (float)U;                          \
        if (Pq) {                                                              \
            const float du = fabsf((float)U - 1.0f);                           \
            const float dd = 1.0f + 0.03f * du;                                \
            const float pv = __expf(-0.05f * (float)(T_STEPS - 1 - t)) / (dd * dd); \
            const unsigned int hw = f2bf(pv);                                  \
            if ((J) & 1) Pq[(size_t)pos * 64 + (t >> 1)] = plo | (hw << 16);   \
            else plo = hw;                                                     \
        }                                                                      \
        U -= Sv;                                                               \
    }

__global__ __launch_bounds__(256) void lif_pointwise(const double* __restrict__ C,
                                                     float* __restrict__ S_out,
                                                     float* __restrict__ Uh,
                                                     unsigned int* __restrict__ Pq) {
    const int pos = blockIdx.x * 256 + threadIdx.x;   // b*OUT + o
    const size_t N = (size_t)B_N * OUT_F;

    double I = 0.0, U = 0.0;
    double bufA[10], bufB[10];
    unsigned int plo = 0;

#pragma unroll
    for (int j = 0; j < 10; ++j) bufA[j] = C[(size_t)j * N + pos];

    for (int cb = 0; cb < 10; cb += 2) {
#pragma unroll
        for (int j = 0; j < 10; ++j) bufB[j] = C[((size_t)(cb + 1) * 10 + j) * N + pos];
#pragma unroll
        for (int j = 0; j < 10; ++j) LIF_STEP(bufA, j, cb)
        if (cb + 2 < 10) {
#pragma unroll
            for (int j = 0; j < 10; ++j) bufA[j] = C[((size_t)(cb + 2) * 10 + j) * N + pos];
        }
#pragma unroll
        for (int j = 0; j < 10; ++j) LIF_STEP(bufB, j, cb + 1)
    }

    if (Pq) {   // zero-pad t = 100..127 (slots 50..63)
#pragma unroll
        for (int k = 0; k < 14; ++k) Pq[(size_t)pos * 64 + 50 + k] = 0u;
    }
}

// ---------------------------------------------------------------------------
// K3: trace[b] = P^T @ X with BLOCK-LOCAL reuse. One block per (b, 128-o
// panel): 512 blocks = 2/CU exact. P panel (32 KB) staged once, its MFMA
// A-fragments hoisted to registers ONCE (reused across all 8 i-tiles);
// X tiles (16 KB) double-buffered: global->reg issued at loop top (hides
// under MFMA), ds_write after compute, one barrier per iter. HBM reads drop
// 196 MB -> 84 MB and no longer depend on L2 surviving the 134 MB write
// stream. Same XOR swizzle ((row&7)<<4 on byte offset) on write & read.
// ---------------------------------------------------------------------------
__global__ __launch_bounds__(256) void trace_mfma3(const unsigned short* __restrict__ Pbf,
                                                   const unsigned short* __restrict__ Xbf,
                                                   float* __restrict__ trace) {
    __shared__ char smem[65536];
    char* const Pl = smem;            // [128][256B] P panel, swz, 32 KB
    char* const X0 = smem + 32768;    // [64][256B] X tile buf0, 16 KB
    char* const X1 = smem + 49152;    // buf1, 16 KB

    const int idx = blockIdx.x;       // 512 blocks
    const int xcd = idx & 7;
    const int s   = idx >> 3;         // 0..63
    const int b   = xcd * 16 + (s >> 2);
    const int ot  = s & 3;
    const int tid = threadIdx.x;

    const char* const Pg  = (const char*)Pbf + (size_t)(b * OUT_F + ot * 128) * 256;
    const char* const Xgb = (const char*)Xbf + (size_t)b * IN_F * 256;

    // ---- stage P panel (128 rows) + X tile 0 (64 rows), swizzled ----
#pragma unroll
    for (int r = 0; r < 8; ++r) {
        const int chunk = tid + r * 256;       // 2048 = 128 rows x 16 chunks
        const int row   = chunk >> 4;
        const int c     = chunk & 15;
        const unsigned int loff = (unsigned int)(row * 256) +
            ((unsigned int)(c * 16) ^ ((unsigned int)(row & 7) << 4));
        *(uint4*)(Pl + loff) = *(const uint4*)(Pg + (size_t)row * 256 + c * 16);
    }
#pragma unroll
    for (int r = 0; r < 4; ++r) {
        const int chunk = tid + r * 256;       // 1024 = 64 rows x 16 chunks
        const int row   = chunk >> 4;
        const int c     = chunk & 15;
        const unsigned int loff = (unsigned int)(row * 256) +
            ((unsigned int)(c * 16) ^ ((unsigned int)(row & 7) << 4));
        *(uint4*)(X0 + loff) = *(const uint4*)(Xgb + (size_t)row * 256 + c * 16);
    }
    __syncthreads();

    const int w    = tid >> 6;                 // 0..3: o rows [w*32, w*32+32)
    const int l    = tid & 63;
    const int lo16 = l & 15;
    const int g4   = l >> 4;                   // 0..3

    // ---- hoist P fragments to registers ONCE (reused for all 8 i-tiles) ----
    bf16x8 af[2][4];
#pragma unroll
    for (int m = 0; m < 2; ++m) {
        const int row = w * 32 + m * 16 + lo16;
#pragma unroll
        for (int kk = 0; kk < 4; ++kk) {
            const unsigned int off = (unsigned int)(row * 256 + kk * 64 + g4 * 16)
                                     ^ ((unsigned int)(row & 7) << 4);
            af[m][kk] = *(const bf16x8*)(Pl + off);
        }
    }

    float* const tbase = trace + (size_t)b * (OUT_F * IN_F) + (size_t)(ot * 128) * IN_F;

    for (int it = 0; it < 8; ++it) {
        char* const Xc = (it & 1) ? X1 : X0;
        char* const Xn = (it & 1) ? X0 : X1;

        // issue next tile's global loads early (land during MFMA below)
        uint4 xr0, xr1, xr2, xr3;
        int nrow0 = 0, nc0 = 0, nrow1 = 0, nc1 = 0, nrow2 = 0, nc2 = 0, nrow3 = 0, nc3 = 0;
        if (it < 7) {
            const char* const Xgn = Xgb + (size_t)(it + 1) * 64 * 256;
            {   const int chunk = tid;           nrow0 = chunk >> 4; nc0 = chunk & 15;
                xr0 = *(const uint4*)(Xgn + (size_t)nrow0 * 256 + nc0 * 16); }
            {   const int chunk = tid + 256;     nrow1 = chunk >> 4; nc1 = chunk & 15;
                xr1 = *(const uint4*)(Xgn + (size_t)nrow1 * 256 + nc1 * 16); }
            {   const int chunk = tid + 512;     nrow2 = chunk >> 4; nc2 = chunk & 15;
                xr2 = *(const uint4*)(Xgn + (size_t)nrow2 * 256 + nc2 * 16); }
            {   const int chunk = tid + 768;     nrow3 = chunk >> 4; nc3 = chunk & 15;
                xr3 = *(const uint4*)(Xgn + (size_t)nrow3 * 256 + nc3 * 16); }
        }

        // ---- compute 128(o) x 64(i) tile ----
        f32x4 acc[2][4];
#pragma unroll
        for (int m = 0; m < 2; ++m)
#pragma unroll
            for (int n = 0; n < 4; ++n) acc[m][n] = (f32x4){0.f, 0.f, 0.f, 0.f};

#pragma unroll
        for (int kk = 0; kk < 4; ++kk) {
            bf16x8 bfr[4];
#pragma unroll
            for (int n = 0; n < 4; ++n) {
                const int row = n * 16 + lo16;
                const unsigned int off = (unsigned int)(row * 256 + kk * 64 + g4 * 16)
                                         ^ ((unsigned int)(row & 7) << 4);
                bfr[n] = *(const bf16x8*)(Xc + off);
            }
#pragma unroll
            for (int m = 0; m < 2; ++m)
#pragma unroll
                for (int n = 0; n < 4; ++n)
                    acc[m][n] = __builtin_amdgcn_mfma_f32_16x16x32_bf16(af[m][kk], bfr[n], acc[m][n], 0, 0, 0);
        }

        // ---- ds_write next tile (buffer not read since before last barrier) ----
        if (it < 7) {
            *(uint4*)(Xn + ((unsigned int)(nrow0 * 256) + ((unsigned int)(nc0 * 16) ^ ((unsigned int)(nrow0 & 7) << 4)))) = xr0;
            *(uint4*)(Xn + ((unsigned int)(nrow1 * 256) + ((unsigned int)(nc1 * 16) ^ ((unsigned int)(nrow1 & 7) << 4)))) = xr1;
            *(uint4*)(Xn + ((unsigned int)(nrow2 * 256) + ((unsigned int)(nc2 * 16) ^ ((unsigned int)(nrow2 & 7) << 4)))) = xr2;
            *(uint4*)(Xn + ((unsigned int)(nrow3 * 256) + ((unsigned int)(nc3 * 16) ^ ((unsigned int)(nrow3 & 7) << 4)))) = xr3;
        }

        // ---- store tile (4 x 64B segments per instruction) ----
#pragma unroll
        for (int m = 0; m < 2; ++m)
#pragma unroll
            for (int rr = 0; rr < 4; ++rr) {
                const int o = w * 32 + m * 16 + g4 * 4 + rr;
                float* const orow = tbase + (size_t)o * IN_F + it * 64 + lo16;
#pragma unroll
                for (int n = 0; n < 4; ++n)
                    __builtin_nontemporal_store(acc[m][n][rr], orow + n * 16);
            }

        if (it < 7) __syncthreads();
    }
}

// ---------------------------------------------------------------------------
// K3 (fallback, ws too small): round-4 kernel — inline f32 staging+convert.
// ---------------------------------------------------------------------------
__global__ __launch_bounds__(256) void trace_mfma(const float* __restrict__ x,
                                                  const float* __restrict__ Uh,
                                                  float* __restrict__ trace) {
    __shared__ unsigned short Pa[128 * 128];
    __shared__ unsigned short Xb[128 * 128];

    const int idx  = blockIdx.x;
    const int xcd  = idx & 7;
    const int slot = idx >> 3;
    const int b    = xcd * 16 + (slot >> 4);
    const int tile = slot & 15;
    const int ot   = tile >> 2;
    const int it   = tile & 3;
    const int tid  = threadIdx.x;

    char* const pbase = (char*)Pa;
    char* const xbase = (char*)Xb;

#pragma unroll
    for (int r = 0; r < 8; ++r) {
        const int g  = tid + r * 256;
        const int i  = g & 127;
        const int kg = g >> 7;
        unsigned int h[4];
#pragma unroll
        for (int jj = 0; jj < 4; ++jj) {
            const int t0 = kg * 8 + jj * 2, t1 = t0 + 1;
            float v0 = 0.f, v1 = 0.f;
            if (t0 < T_STEPS) v0 = x[(size_t)t0 * (B_N * IN_F) + b * IN_F + it * 128 + i];
            if (t1 < T_STEPS) v1 = x[(size_t)t1 * (B_N * IN_F) + b * IN_F + it * 128 + i];
            h[jj] = f2bf(v0) | (f2bf(v1) << 16);
        }
        unsigned int off = (unsigned int)(i * 256 + kg * 16) ^ ((unsigned int)(i & 7) << 4);
        *(uint4*)(xbase + off) = make_uint4(h[0], h[1], h[2], h[3]);
    }

#pragma unroll
    for (int r = 0; r < 8; ++r) {
        const int g  = tid + r * 256;
        const int o  = g & 127;
        const int kg = g >> 7;
        unsigned int h[4];
#pragma unroll
        for (int jj = 0; jj < 4; ++jj) {
            unsigned int hw[2];
#pragma unroll
            for (int e = 0; e < 2; ++e) {
                const int t = kg * 8 + jj * 2 + e;
                float p = 0.f;
                if (t < T_STEPS) {
                    const float u  = Uh[(size_t)(2 * t + 1) * (B_N * OUT_F) + b * OUT_F + ot * 128 + o];
                    const float du = fabsf(u - 1.0f);
                    const float d  = 1.0f + 0.03f * du;
                    const float gp = __expf(-0.05f * (float)(T_STEPS - 1 - t));
                    p = gp / (d * d);
                }
                hw[e] = f2bf(p);
            }
            h[jj] = hw[0] | (hw[1] << 16);
        }
        unsigned int off = (unsigned int)(o * 256 + kg * 16) ^ ((unsigned int)(o & 7) << 4);
        *(uint4*)(pbase + off) = make_uint4(h[0], h[1], h[2], h[3]);
    }
    __syncthreads();

    const int w    = tid >> 6;
    const int l    = tid & 63;
    const int wo   = (w >> 1) * 64;
    const int wi   = (w & 1) * 64;
    const int lo16 = l & 15;
    const int g4   = l >> 4;

    f32x4 acc[4][4];
#pragma unroll
    for (int m = 0; m < 4; ++m)
#pragma unroll
        for (int n = 0; n < 4; ++n) acc[m][n] = (f32x4){0.f, 0.f, 0.f, 0.f};

#pragma unroll
    for (int kk = 0; kk < 4; ++kk) {
        bf16x8 af[4], bfr[4];
#pragma unroll
        for (int m = 0; m < 4; ++m) {
            const int row = wo + m * 16 + lo16;
            const unsigned int off = (unsigned int)(row * 256 + kk * 64 + g4 * 16)
                                     ^ ((unsigned int)(row & 7) << 4);
            af[m] = *(const bf16x8*)(pbase + off);
        }
#pragma unroll
        for (int n = 0; n < 4; ++n) {
            const int row = wi + n * 16 + lo16;
            const unsigned int off = (unsigned int)(row * 256 + kk * 64 + g4 * 16)
                                     ^ ((unsigned int)(row & 7) << 4);
            bfr[n] = *(const bf16x8*)(xbase + off);
        }
#pragma unroll
        for (int m = 0; m < 4; ++m)
#pragma unroll
            for (int n = 0; n < 4; ++n)
                acc[m][n] = __builtin_amdgcn_mfma_f32_16x16x32_bf16(af[m], bfr[n], acc[m][n], 0, 0, 0);
    }

    float* tb = trace + (size_t)b * (OUT_F * IN_F);
#pragma unroll
    for (int m = 0; m < 4; ++m) {
#pragma unroll
        for (int rr = 0; rr < 4; ++rr) {
            const int o = ot * 128 + wo + m * 16 + g4 * 4 + rr;
#pragma unroll
            for (int n = 0; n < 4; ++n) {
                const int i = it * 128 + wi + n * 16 + lo16;
                tb[(size_t)o * IN_F + i] = acc[m][n][rr];
            }
        }
    }
}

// ---------------------------------------------------------------------------
extern "C" void kernel_launch(void* const* d_in, const int* in_sizes, int n_in,
                              void* d_out, int out_size, void* d_ws, size_t ws_size,
                              hipStream_t stream) {
    const float* x = (const float*)d_in[0];   // (T, B, IN) binary spikes
    const float* W = (const float*)d_in[1];   // (OUT, IN)

    float* out   = (float*)d_out;
    float* S_out = out;                                            // (T, B, OUT)
    float* Uh    = out + (size_t)T_STEPS * B_N * OUT_F;            // (2T, B, OUT)
    float* trace = Uh + (size_t)2 * T_STEPS * B_N * OUT_F;         // (B, OUT, IN)

    // ws layout: Wt (1 MB) | Xbf (16.78 MB) | Pbf (16.78 MB)
    const size_t WT_BYTES = (size_t)IN_F * OUT_F * 4;
    const size_t BF_BYTES = (size_t)B_N * 512 * KPAD * 2;          // 16,777,216
    const bool   ws_ok    = ws_size >= WT_BYTES + 2 * BF_BYTES;

    float*          Wt  = (float*)d_ws;
    unsigned short* Xbf = (unsigned short*)((char*)d_ws + WT_BYTES);
    unsigned short* Pbf = (unsigned short*)((char*)d_ws + WT_BYTES + BF_BYTES);

    // C scratch: reuse the trace region of d_out (134 MB >= 52 MB needed);
    // the trace kernel runs last and overwrites it.
    double* C = (double*)trace;

    const int nconv = ws_ok ? 512 : 0;

    transposeW<<<256, 256, 0, stream>>>(W, Wt);
    syn_plus<<<T_STEPS * B_N + nconv, 256, 0, stream>>>(x, Wt, C, Xbf, nconv);
    lif_pointwise<<<B_N * OUT_F / 256, 256, 0, stream>>>(C, S_out, Uh,
                                                         ws_ok ? (unsigned int*)Pbf : nullptr);
    if (ws_ok)
        trace_mfma3<<<512, 256, 0, stream>>>(Pbf, Xbf, trace);
    else
        trace_mfma<<<16 * B_N, 256, 0, stream>>>(x, Uh, trace);
}